// Round 8
// baseline (786.290 us; speedup 1.0000x reference)
//
#include <hip/hip_runtime.h>
#include <hip/hip_bf16.h>

// Problem constants
#define BB 4
#define TT 2048
#define DD 1024
#define HH 16
#define SS 64
#define CH 64
#define NC (TT/CH)        // 32
#define M_ROWS (BB*TT)    // 8192

typedef __hip_bfloat16 bf16;
using short8 = __attribute__((ext_vector_type(8))) short;   // 8 bf16 (4 VGPRs)
using f32x4  = __attribute__((ext_vector_type(4))) float;

static __device__ __forceinline__ float b2f(bf16 v) { return __bfloat162float(v); }

#if defined(__has_builtin)
#if __has_builtin(__builtin_amdgcn_global_load_lds)
#define HAVE_GLL 1
#endif
#endif

#ifdef HAVE_GLL
// async global->LDS, 16 B per lane; LDS dst is wave-uniform base + lane*16
static __device__ __forceinline__ void gload16(const void* g, void* l) {
  __builtin_amdgcn_global_load_lds(
      (const __attribute__((address_space(1))) void*)g,
      (__attribute__((address_space(3))) void*)l, 16, 0, 0);
}
#endif

// ---- block-wide sum over 256 threads (deterministic tree) ----
static __device__ __forceinline__ float block_sum(float v, float* red) {
  int tid = threadIdx.x;
  red[tid] = v; __syncthreads();
  #pragma unroll
  for (int o = 128; o > 0; o >>= 1) {
    if (tid < o) red[tid] += red[tid + o];
    __syncthreads();
  }
  float r = red[0];
  __syncthreads();
  return r;
}

// ---- K1a: weight-scale partials. grid (5,64) ----
__global__ __launch_bounds__(256) void k_wscale_part(const float* __restrict__ w,
                                                     double* __restrict__ wpart) {
  __shared__ double red[256];
  int i = blockIdx.x, b = blockIdx.y, tid = threadIdx.x;
  const float* base = w + (size_t)i * DD * DD + (size_t)b * 16384;
  double s = 0.0;
  #pragma unroll
  for (int j = 0; j < 64; j++) s += (double)fabsf(base[tid + j * 256]);
  red[tid] = s; __syncthreads();
  for (int o = 128; o > 0; o >>= 1) {
    if (tid < o) red[tid] += red[tid + o];
    __syncthreads();
  }
  if (tid == 0) wpart[i * 64 + b] = red[0];
}

// ---- K1b: fold 64 partials per matrix in fixed order ----
__global__ __launch_bounds__(64) void k_wscale_fin(const double* __restrict__ wpart,
                                                   float* __restrict__ wscale) {
  int i = blockIdx.x;
  if (threadIdx.x == 0) {
    double s = 0.0;
    for (int b = 0; b < 64; b++) s += wpart[i * 64 + b];
    wscale[i] = fmaxf((float)(s * (1.0 / (DD * DD))), 1e-8f);
  }
}

// ---- K2: ternary weight quant, stored as exact bf16 {-1,0,1} ----
__global__ __launch_bounds__(256) void k_wquant(const float* __restrict__ w,
                                                const float* __restrict__ wscale,
                                                bf16* __restrict__ wq) {
  int idx = blockIdx.x * 256 + threadIdx.x;   // < 5*1024*1024
  int i = idx >> 20;
  float ws = wscale[i];
  float wn = w[idx] / ws;
  wn = fminf(fmaxf(wn, -1.f), 1.f);
  wq[idx] = __float2bfloat16(rintf(wn));
}

// ---- K3: token-shift mix + LayerNorm + activation quant ----
__global__ __launch_bounds__(256) void k_prep_quant(
    const float* __restrict__ x, const float* __restrict__ mu_r,
    const float* __restrict__ mu_k, const float* __restrict__ mu_v,
    const float* __restrict__ mu_g, const float* __restrict__ ln_g,
    const float* __restrict__ ln_b, bf16* __restrict__ xq,
    float* __restrict__ ascale) {
  __shared__ float red[256];
  int m = blockIdx.x, i = blockIdx.y, tid = threadIdx.x;
  int t = m & (TT - 1);
  const float* mu = (i == 0) ? mu_r : (i == 1) ? mu_k : (i == 2) ? mu_v : mu_g;
  const float* xr = x + (size_t)m * DD;
  const float* lg = ln_g + i * DD;
  const float* lb = ln_b + i * DD;
  float inp[4];
  #pragma unroll
  for (int j = 0; j < 4; j++) {
    int d = tid + j * 256;
    float xv = xr[d];
    float xs = (t > 0) ? xr[d - DD] : 0.f;
    inp[j] = xv + (xs - xv) * mu[d];
  }
  float mean = block_sum(inp[0] + inp[1] + inp[2] + inp[3], red) * (1.f / DD);
  float var = 0.f;
  #pragma unroll
  for (int j = 0; j < 4; j++) { float dv = inp[j] - mean; var += dv * dv; }
  var = block_sum(var, red) * (1.f / DD);
  float rstd = 1.f / sqrtf(var + 1e-5f);
  float ln[4]; float aabs = 0.f;
  #pragma unroll
  for (int j = 0; j < 4; j++) {
    int d = tid + j * 256;
    ln[j] = (inp[j] - mean) * rstd * lg[d] + lb[d];
    aabs += fabsf(ln[j]);
  }
  float meanabs = block_sum(aabs, red) * (1.f / DD);
  float scale = fmaxf(meanabs, 1e-8f) * 2.5f * (1.f / 127.f);
  bf16* xo = xq + ((size_t)i * M_ROWS + m) * DD;
  #pragma unroll
  for (int j = 0; j < 4; j++) {
    int d = tid + j * 256;
    float q = rintf(fminf(fmaxf(ln[j] / scale, -127.f), 127.f));
    xo[d] = __float2bfloat16(q);              // exact: |int| <= 127
  }
  if (tid == 0) ascale[i * M_ROWS + m] = scale;
}

// ---- K4/K9: bf16 MFMA GEMM, 128x128 tile + async global->LDS staging (m97 step).
// Unpadded LDS (stride 32 shorts) so the wave's lane->LDS mapping is contiguous,
// as global_load_lds requires. Fragment/data layout identical to R6/R7 (validated). ----
__global__ __launch_bounds__(256) void k_gemm(
    const bf16* __restrict__ Axq, const bf16* __restrict__ Wq,
    const float* __restrict__ ascale, const float* __restrict__ wscale,
    int projbase, float* __restrict__ outF) {
  __shared__ short As[128 * 32];
  __shared__ short Bs[128 * 32];
  int tid = threadIdx.x;
  int wvid = tid >> 6, lane = tid & 63;
  int wm = wvid >> 1, wn = wvid & 1;
  int m0 = blockIdx.x * 128, n0 = blockIdx.y * 128;
  int z = blockIdx.z;
  int proj = projbase + z;
  const bf16* Ap = Axq + ((size_t)z * M_ROWS + m0) * DD;
  const bf16* Wp = Wq + ((size_t)proj * DD + n0) * DD;
  f32x4 acc[4][4];
  #pragma unroll
  for (int i = 0; i < 4; i++)
    #pragma unroll
    for (int j = 0; j < 4; j++) acc[i][j] = (f32x4){0.f, 0.f, 0.f, 0.f};
  int row = tid >> 2, cg8 = (tid & 3) * 8;    // staging: 16B/thread/issue
  int frow = lane & 15, fq8 = (lane >> 4) * 8;
  for (int k0 = 0; k0 < DD; k0 += 32) {
#ifdef HAVE_GLL
    #pragma unroll
    for (int q = 0; q < 2; q++) {
      gload16(&Ap[(size_t)(q * 64 + row) * DD + k0 + cg8], &As[tid * 8 + q * 2048]);
      gload16(&Wp[(size_t)(q * 64 + row) * DD + k0 + cg8], &Bs[tid * 8 + q * 2048]);
    }
#else
    #pragma unroll
    for (int q = 0; q < 2; q++) {
      *(uint4*)&As[(q * 64 + row) * 32 + cg8] =
          *(const uint4*)&Ap[(size_t)(q * 64 + row) * DD + k0 + cg8];
      *(uint4*)&Bs[(q * 64 + row) * 32 + cg8] =
          *(const uint4*)&Wp[(size_t)(q * 64 + row) * DD + k0 + cg8];
    }
#endif
    __syncthreads();
    short8 af[4], bfr[4];
    #pragma unroll
    for (int i = 0; i < 4; i++)
      af[i] = *(short8*)&As[(64 * wm + 16 * i + frow) * 32 + fq8];
    #pragma unroll
    for (int j = 0; j < 4; j++)
      bfr[j] = *(short8*)&Bs[(64 * wn + 16 * j + frow) * 32 + fq8];
    #pragma unroll
    for (int i = 0; i < 4; i++)
      #pragma unroll
      for (int j = 0; j < 4; j++)
        acc[i][j] = __builtin_amdgcn_mfma_f32_16x16x32_bf16(af[i], bfr[j], acc[i][j], 0, 0, 0);
    __syncthreads();
  }
  const float* asc = ascale + (size_t)z * M_ROWS + m0;
  float wsc = wscale[proj];
  int col = lane & 15, rg = lane >> 4;
  #pragma unroll
  for (int i = 0; i < 4; i++) {
    #pragma unroll
    for (int r = 0; r < 4; r++) {
      int mm = 64 * wm + 16 * i + rg * 4 + r;
      float s = asc[mm] * wsc;
      #pragma unroll
      for (int j = 0; j < 4; j++) {
        int nn = 64 * wn + 16 * j + col;
        outF[((size_t)z * M_ROWS + m0 + mm) * DD + (n0 + nn)] = acc[i][j][r] * s;
      }
    }
  }
}

// ---- K5: per-chunk injection  inj[s,o] = sum_c w^{63-c} k[c,s] v[c,o] ----
__global__ __launch_bounds__(256) void k_inj(const float* __restrict__ rkvg,
                                             const float* __restrict__ log_decay,
                                             float* __restrict__ states) {
  __shared__ float ksh[CH * SS], vsh[CH * SS];
  int blk = blockIdx.x, tid = threadIdx.x;
  int n = blk & (NC - 1), h = (blk >> 5) & (HH - 1), b = blk >> 9;
  size_t rowbase = ((size_t)b * TT + n * CH) * DD + h * SS;
  const float* Kp = rkvg + (size_t)1 * M_ROWS * DD + rowbase;
  const float* Vp = rkvg + (size_t)2 * M_ROWS * DD + rowbase;
  for (int idx = tid; idx < CH * SS; idx += 256) {
    int c = idx >> 6, s2 = idx & 63;
    ksh[idx] = Kp[(size_t)c * DD + s2];
    vsh[idx] = Vp[(size_t)c * DD + s2];
  }
  int o = tid & 63, sg = tid >> 6;
  float wv[16], acc[16];
  #pragma unroll
  for (int j = 0; j < 16; j++) {
    int s2 = sg * 16 + j;
    float e = expf(log_decay[h * SS + s2]);
    wv[j] = expf(-e); acc[j] = 0.f;
  }
  __syncthreads();
  for (int c = 0; c < CH; c++) {
    float vvv = vsh[c * SS + o];
    #pragma unroll
    for (int j = 0; j < 16; j++)
      acc[j] = wv[j] * acc[j] + ksh[c * SS + sg * 16 + j] * vvv;
  }
  float* st = states + (size_t)blk * SS * SS;
  #pragma unroll
  for (int j = 0; j < 16; j++) st[(size_t)(sg * 16 + j) * SS + o] = acc[j];
}

// ---- K6: in-place scan over chunks ----
__global__ __launch_bounds__(256) void k_scan(const float* __restrict__ log_decay,
                                              float* __restrict__ states) {
  int bh = blockIdx.x, tid = threadIdx.x;
  int h = bh & (HH - 1);
  int o = tid & 63, sg = tid >> 6;
  float wC[16], cur[16];
  #pragma unroll
  for (int j = 0; j < 16; j++) {
    int s2 = sg * 16 + j;
    float e = expf(log_decay[h * SS + s2]);
    wC[j] = expf(-64.f * e);
    cur[j] = 0.f;
  }
  float* base = states + (size_t)bh * NC * SS * SS;
  for (int n = 0; n < NC; n++) {
    float* p = base + (size_t)n * SS * SS;
    #pragma unroll
    for (int j = 0; j < 16; j++) {
      size_t ii = (size_t)(sg * 16 + j) * SS + o;
      float inj = p[ii];
      p[ii] = cur[j];
      cur[j] = wC[j] * cur[j] + inj;
    }
  }
}

// ---- K7 v4: lean WKV. LDS 48.5 KB -> 3 blocks/CU. v from global per tile.
// Cross-wave reduce via native LDS float atomicAdd (ds_add_f32) into yacc.
// 3 barriers total; a[16] scan state in VGPRs; 2-way split p-chain. ----
__global__ __launch_bounds__(256) void k_wkv_y(const float* __restrict__ rkvg,
                                               const float* __restrict__ log_decay,
                                               const float* __restrict__ u,
                                               const float* __restrict__ states,
                                               float* __restrict__ Y) {
  __shared__ float rsh[CH * SS], ksh[CH * SS];
  __shared__ float yacc[CH * SS];
  __shared__ float betash[CH], eush[SS];
  int blk = blockIdx.x, tid = threadIdx.x;
  int n = blk & (NC - 1), h = (blk >> 5) & (HH - 1), b = blk >> 9;
  size_t rowbase = ((size_t)b * TT + n * CH) * DD + h * SS;
  const float* Rp = rkvg + rowbase;
  const float* Kp = rkvg + (size_t)1 * M_ROWS * DD + rowbase;
  const float* Vp = rkvg + (size_t)2 * M_ROWS * DD + rowbase;
  for (int idx = tid; idx < CH * SS; idx += 256) {
    int c = idx >> 6, s2 = idx & 63;
    rsh[idx] = Rp[(size_t)c * DD + s2];
    ksh[idx] = Kp[(size_t)c * DD + s2];
    yacc[idx] = 0.f;
  }
  if (tid < SS) eush[tid] = expf(u[h * SS + tid]);
  __syncthreads();
  // beta[t] = sum_s r[t,s]k[t,s]eu[s]; diagonal access -> conflict-free
  if (tid < CH) {
    float s = 0.f;
    for (int q = 0; q < SS; q++) {
      int s2 = (q + tid) & 63;
      s += rsh[tid * SS + s2] * ksh[tid * SS + s2] * eush[s2];
    }
    betash[tid] = s;
  }
  __syncthreads();

  int o = tid & 63, sg = tid >> 6, S0 = sg * 16;
  float wv[16];
  #pragma unroll
  for (int j = 0; j < 16; j++) wv[j] = expf(-expf(log_decay[h * SS + S0 + j]));

  // ---- pass A: backward suffix scan over tiles of 8 t; v from global ----
  float a[16];
  #pragma unroll
  for (int j = 0; j < 16; j++) a[j] = 0.f;
  for (int ti = 7; ti >= 0; ti--) {
    float v8[8];
    #pragma unroll
    for (int tt = 0; tt < 8; tt++)
      v8[tt] = Vp[(size_t)(ti * 8 + tt) * DD + o];
    #pragma unroll
    for (int tt = 7; tt >= 0; tt--) {
      int t = ti * 8 + tt;
      float v = v8[tt];
      float acc0 = 0.f, acc1 = 0.f;
      #pragma unroll
      for (int q = 0; q < 4; q++) {
        float4 k4 = *(const float4*)&ksh[t * SS + S0 + q * 4];
        float4 r4 = *(const float4*)&rsh[t * SS + S0 + q * 4];
        float kk[4] = {k4.x, k4.y, k4.z, k4.w};
        float rr[4] = {r4.x, r4.y, r4.z, r4.w};
        #pragma unroll
        for (int e = 0; e < 4; e++) {
          int j = q * 4 + e;
          a[j] = fmaf(wv[j], a[j], kk[e] * v);
          if (q < 2) acc0 = fmaf(rr[e], a[j], acc0);
          else       acc1 = fmaf(rr[e], a[j], acc1);
        }
      }
      float p = acc0 + acc1;
      if (sg == 0) p = fmaf(betash[t], v, p);
      atomicAdd(&yacc[t * SS + o], p);          // ds_add_f32
    }
  }
  // ---- pass B: forward cross-chunk term ----
  const float* stp = states + (size_t)blk * SS * SS;
  float st[16], pw[16];
  #pragma unroll
  for (int j = 0; j < 16; j++) {
    st[j] = stp[(size_t)(S0 + j) * SS + o];
    pw[j] = wv[j];                              // w^{t+1} at t=0
  }
  #pragma unroll 4
  for (int t = 0; t < CH; t++) {
    float acc0 = 0.f, acc1 = 0.f;
    #pragma unroll
    for (int q = 0; q < 4; q++) {
      float4 r4 = *(const float4*)&rsh[t * SS + S0 + q * 4];
      float rr[4] = {r4.x, r4.y, r4.z, r4.w};
      #pragma unroll
      for (int e = 0; e < 4; e++) {
        int j = q * 4 + e;
        if (q < 2) acc0 = fmaf(rr[e], pw[j] * st[j], acc0);
        else       acc1 = fmaf(rr[e], pw[j] * st[j], acc1);
        pw[j] *= wv[j];
      }
    }
    atomicAdd(&yacc[t * SS + o], acc0 + acc1);
  }
  __syncthreads();
  // ---- final coalesced write ----
  float* Yb = Y + ((size_t)b * TT + n * CH) * DD + h * SS;
  #pragma unroll
  for (int it = 0; it < 16; it++) {
    int idx = tid + it * 256;                   // (t, o)
    int t = idx >> 6, o2 = idx & 63;
    Yb[(size_t)t * DD + o2] = yacc[idx];
  }
}

// ---- K8: GroupNorm + silu(g) + LayerNorm + act-quant ----
__global__ __launch_bounds__(256) void k_post(const float* __restrict__ Y,
                                              const float* __restrict__ G,
                                              const float* __restrict__ gn_g,
                                              const float* __restrict__ gn_b,
                                              const float* __restrict__ lg,
                                              const float* __restrict__ lb,
                                              bf16* __restrict__ xq4,
                                              float* __restrict__ ascale4) {
  __shared__ float red[256];
  __shared__ float ysh[DD];
  __shared__ float gmean[HH], grstd[HH];
  int m = blockIdx.x, tid = threadIdx.x;
  const float* Yr = Y + (size_t)m * DD;
  const float* Gr = G + (size_t)m * DD;
  #pragma unroll
  for (int j = 0; j < 4; j++) { int d = tid + j * 256; ysh[d] = Yr[d]; }
  __syncthreads();
  if (tid < HH) {
    float s = 0.f;
    for (int q2 = 0; q2 < SS; q2++) s += ysh[tid * SS + ((q2 + tid * 4) & 63)];
    float mn = s * (1.f / SS);
    float v2 = 0.f;
    for (int q2 = 0; q2 < SS; q2++) {
      float dv = ysh[tid * SS + ((q2 + tid * 4) & 63)] - mn; v2 += dv * dv;
    }
    gmean[tid] = mn;
    grstd[tid] = 1.f / sqrtf(v2 * (1.f / SS) + 1e-5f);
  }
  __syncthreads();
  float z[4];
  #pragma unroll
  for (int j = 0; j < 4; j++) {
    int d = tid + j * 256; int hh = d >> 6;
    float yn = (ysh[d] - gmean[hh]) * grstd[hh] * gn_g[d] + gn_b[d];
    float gv = Gr[d];
    z[j] = yn * (gv / (1.f + expf(-gv)));            // silu
  }
  float mean = block_sum(z[0] + z[1] + z[2] + z[3], red) * (1.f / DD);
  float var = 0.f;
  #pragma unroll
  for (int j = 0; j < 4; j++) { float dv = z[j] - mean; var += dv * dv; }
  var = block_sum(var, red) * (1.f / DD);
  float rstd = 1.f / sqrtf(var + 1e-5f);
  float ln[4]; float aabs = 0.f;
  #pragma unroll
  for (int j = 0; j < 4; j++) {
    int d = tid + j * 256;
    ln[j] = (z[j] - mean) * rstd * lg[d] + lb[d];
    aabs += fabsf(ln[j]);
  }
  float meanabs = block_sum(aabs, red) * (1.f / DD);
  float scale = fmaxf(meanabs, 1e-8f) * 2.5f * (1.f / 127.f);
  #pragma unroll
  for (int j = 0; j < 4; j++) {
    int d = tid + j * 256;
    xq4[(size_t)m * DD + d] =
        __float2bfloat16(rintf(fminf(fmaxf(ln[j] / scale, -127.f), 127.f)));
  }
  if (tid == 0) ascale4[m] = scale;
}

extern "C" void kernel_launch(void* const* d_in, const int* in_sizes, int n_in,
                              void* d_out, int out_size, void* d_ws, size_t ws_size,
                              hipStream_t stream) {
  // ALL inputs are float32 (verified R4); output float32.
  const float* x         = (const float*)d_in[0];
  const float* mu_r      = (const float*)d_in[1];
  const float* mu_k      = (const float*)d_in[2];
  const float* mu_v      = (const float*)d_in[3];
  const float* mu_g      = (const float*)d_in[4];
  const float* log_decay = (const float*)d_in[5];
  const float* u         = (const float*)d_in[6];
  const float* proj_w    = (const float*)d_in[7];
  const float* ln_g      = (const float*)d_in[8];
  const float* ln_b      = (const float*)d_in[9];
  const float* gn_g      = (const float*)d_in[10];
  const float* gn_b      = (const float*)d_in[11];
  float* out = (float*)d_out;

  // ---- workspace layout, ~234 MiB total; U region (64 MB) time-multiplexed ----
  char* p = (char*)d_ws;
  float*  wscale = (float*)p;  p += 256;                         // 5 f32
  double* wpart  = (double*)p; p += 4096;                        // 5*64 f64
  bf16*   wq     = (bf16*)p;   p += (size_t)5 * DD * DD * 2;     // 10 MB
  float*  ascale = (float*)p;  p += (size_t)5 * M_ROWS * 4;      // 160 KB
  char*   U      = p;          p += (size_t)4 * M_ROWS * DD * 2; // 64 MB
  bf16*   xq     = (bf16*)U;
  float*  Y      = (float*)U;
  bf16*   xq4    = (bf16*)(U + (size_t)M_ROWS * DD * 4);         // U + 32 MB
  float*  rkvg   = (float*)p;  p += (size_t)4 * M_ROWS * DD * 4; // 128 MB
  float*  states = (float*)p;  p += (size_t)BB * HH * NC * SS * SS * 4; // 32 MB

  hipLaunchKernelGGL(k_wscale_part, dim3(5, 64), dim3(256), 0, stream, proj_w, wpart);
  hipLaunchKernelGGL(k_wscale_fin, dim3(5), dim3(64), 0, stream, wpart, wscale);
  hipLaunchKernelGGL(k_wquant, dim3((5 * DD * DD) / 256), dim3(256), 0, stream,
                     proj_w, wscale, wq);
  hipLaunchKernelGGL(k_prep_quant, dim3(M_ROWS, 4), dim3(256), 0, stream,
                     x, mu_r, mu_k, mu_v, mu_g, ln_g, ln_b, xq, ascale);
  hipLaunchKernelGGL(k_gemm, dim3(M_ROWS / 128, DD / 128, 4), dim3(256), 0,
                     stream, xq, wq, ascale, wscale, 0, rkvg);
  hipLaunchKernelGGL(k_inj, dim3(BB * HH * NC), dim3(256), 0, stream,
                     rkvg, log_decay, states);
  hipLaunchKernelGGL(k_scan, dim3(BB * HH), dim3(256), 0, stream, log_decay, states);
  hipLaunchKernelGGL(k_wkv_y, dim3(BB * HH * NC), dim3(256), 0, stream,
                     rkvg, log_decay, u, states, Y);
  hipLaunchKernelGGL(k_post, dim3(M_ROWS), dim3(256), 0, stream,
                     Y, rkvg + (size_t)3 * M_ROWS * DD, gn_g, gn_b,
                     ln_g + 4 * DD, ln_b + 4 * DD,
                     xq4, ascale + 4 * M_ROWS);
  hipLaunchKernelGGL(k_gemm, dim3(M_ROWS / 128, DD / 128, 1), dim3(256), 0,
                     stream, xq4, wq,
                     ascale + 4 * M_ROWS, wscale, 4, out);
}

// Round 9
// 487.652 us; speedup vs baseline: 1.6124x; 1.6124x over previous
//
#include <hip/hip_runtime.h>
#include <hip/hip_bf16.h>

// Problem constants
#define BB 4
#define TT 2048
#define DD 1024
#define HH 16
#define SS 64
#define CH 64
#define NC (TT/CH)        // 32
#define M_ROWS (BB*TT)    // 8192

typedef __hip_bfloat16 bf16;
using short8 = __attribute__((ext_vector_type(8))) short;   // 8 bf16 (4 VGPRs)
using f32x4  = __attribute__((ext_vector_type(4))) float;

static __device__ __forceinline__ float b2f(bf16 v) { return __bfloat162float(v); }

#if defined(__has_builtin)
#if __has_builtin(__builtin_amdgcn_global_load_lds)
#define HAVE_GLL 1
#endif
#endif

#ifdef HAVE_GLL
// async global->LDS, 16 B per lane; LDS dst is wave-uniform base + lane*16
static __device__ __forceinline__ void gload16(const void* g, void* l) {
  __builtin_amdgcn_global_load_lds(
      (const __attribute__((address_space(1))) void*)g,
      (__attribute__((address_space(3))) void*)l, 16, 0, 0);
}
#endif

// ---- block-wide sum over 256 threads (deterministic tree) ----
static __device__ __forceinline__ float block_sum(float v, float* red) {
  int tid = threadIdx.x;
  red[tid] = v; __syncthreads();
  #pragma unroll
  for (int o = 128; o > 0; o >>= 1) {
    if (tid < o) red[tid] += red[tid + o];
    __syncthreads();
  }
  float r = red[0];
  __syncthreads();
  return r;
}

// ---- K1a: weight-scale partials. grid (5,64) ----
__global__ __launch_bounds__(256) void k_wscale_part(const float* __restrict__ w,
                                                     double* __restrict__ wpart) {
  __shared__ double red[256];
  int i = blockIdx.x, b = blockIdx.y, tid = threadIdx.x;
  const float* base = w + (size_t)i * DD * DD + (size_t)b * 16384;
  double s = 0.0;
  #pragma unroll
  for (int j = 0; j < 64; j++) s += (double)fabsf(base[tid + j * 256]);
  red[tid] = s; __syncthreads();
  for (int o = 128; o > 0; o >>= 1) {
    if (tid < o) red[tid] += red[tid + o];
    __syncthreads();
  }
  if (tid == 0) wpart[i * 64 + b] = red[0];
}

// ---- K1b: fold 64 partials per matrix in fixed order ----
__global__ __launch_bounds__(64) void k_wscale_fin(const double* __restrict__ wpart,
                                                   float* __restrict__ wscale) {
  int i = blockIdx.x;
  if (threadIdx.x == 0) {
    double s = 0.0;
    for (int b = 0; b < 64; b++) s += wpart[i * 64 + b];
    wscale[i] = fmaxf((float)(s * (1.0 / (DD * DD))), 1e-8f);
  }
}

// ---- K2: ternary weight quant, stored as exact bf16 {-1,0,1} ----
__global__ __launch_bounds__(256) void k_wquant(const float* __restrict__ w,
                                                const float* __restrict__ wscale,
                                                bf16* __restrict__ wq) {
  int idx = blockIdx.x * 256 + threadIdx.x;   // < 5*1024*1024
  int i = idx >> 20;
  float ws = wscale[i];
  float wn = w[idx] / ws;
  wn = fminf(fmaxf(wn, -1.f), 1.f);
  wq[idx] = __float2bfloat16(rintf(wn));
}

// ---- K3: token-shift mix + LayerNorm + activation quant ----
__global__ __launch_bounds__(256) void k_prep_quant(
    const float* __restrict__ x, const float* __restrict__ mu_r,
    const float* __restrict__ mu_k, const float* __restrict__ mu_v,
    const float* __restrict__ mu_g, const float* __restrict__ ln_g,
    const float* __restrict__ ln_b, bf16* __restrict__ xq,
    float* __restrict__ ascale) {
  __shared__ float red[256];
  int m = blockIdx.x, i = blockIdx.y, tid = threadIdx.x;
  int t = m & (TT - 1);
  const float* mu = (i == 0) ? mu_r : (i == 1) ? mu_k : (i == 2) ? mu_v : mu_g;
  const float* xr = x + (size_t)m * DD;
  const float* lg = ln_g + i * DD;
  const float* lb = ln_b + i * DD;
  float inp[4];
  #pragma unroll
  for (int j = 0; j < 4; j++) {
    int d = tid + j * 256;
    float xv = xr[d];
    float xs = (t > 0) ? xr[d - DD] : 0.f;
    inp[j] = xv + (xs - xv) * mu[d];
  }
  float mean = block_sum(inp[0] + inp[1] + inp[2] + inp[3], red) * (1.f / DD);
  float var = 0.f;
  #pragma unroll
  for (int j = 0; j < 4; j++) { float dv = inp[j] - mean; var += dv * dv; }
  var = block_sum(var, red) * (1.f / DD);
  float rstd = 1.f / sqrtf(var + 1e-5f);
  float ln[4]; float aabs = 0.f;
  #pragma unroll
  for (int j = 0; j < 4; j++) {
    int d = tid + j * 256;
    ln[j] = (inp[j] - mean) * rstd * lg[d] + lb[d];
    aabs += fabsf(ln[j]);
  }
  float meanabs = block_sum(aabs, red) * (1.f / DD);
  float scale = fmaxf(meanabs, 1e-8f) * 2.5f * (1.f / 127.f);
  bf16* xo = xq + ((size_t)i * M_ROWS + m) * DD;
  #pragma unroll
  for (int j = 0; j < 4; j++) {
    int d = tid + j * 256;
    float q = rintf(fminf(fmaxf(ln[j] / scale, -127.f), 127.f));
    xo[d] = __float2bfloat16(q);              // exact: |int| <= 127
  }
  if (tid == 0) ascale[i * M_ROWS + m] = scale;
}

// ---- K4/K9: bf16 MFMA GEMM, 128x128 tile + async global->LDS (kept from R8) ----
__global__ __launch_bounds__(256) void k_gemm(
    const bf16* __restrict__ Axq, const bf16* __restrict__ Wq,
    const float* __restrict__ ascale, const float* __restrict__ wscale,
    int projbase, float* __restrict__ outF) {
  __shared__ short As[128 * 32];
  __shared__ short Bs[128 * 32];
  int tid = threadIdx.x;
  int wvid = tid >> 6, lane = tid & 63;
  int wm = wvid >> 1, wn = wvid & 1;
  int m0 = blockIdx.x * 128, n0 = blockIdx.y * 128;
  int z = blockIdx.z;
  int proj = projbase + z;
  const bf16* Ap = Axq + ((size_t)z * M_ROWS + m0) * DD;
  const bf16* Wp = Wq + ((size_t)proj * DD + n0) * DD;
  f32x4 acc[4][4];
  #pragma unroll
  for (int i = 0; i < 4; i++)
    #pragma unroll
    for (int j = 0; j < 4; j++) acc[i][j] = (f32x4){0.f, 0.f, 0.f, 0.f};
  int row = tid >> 2, cg8 = (tid & 3) * 8;    // staging: 16B/thread/issue
  int frow = lane & 15, fq8 = (lane >> 4) * 8;
  for (int k0 = 0; k0 < DD; k0 += 32) {
#ifdef HAVE_GLL
    #pragma unroll
    for (int q = 0; q < 2; q++) {
      gload16(&Ap[(size_t)(q * 64 + row) * DD + k0 + cg8], &As[tid * 8 + q * 2048]);
      gload16(&Wp[(size_t)(q * 64 + row) * DD + k0 + cg8], &Bs[tid * 8 + q * 2048]);
    }
#else
    #pragma unroll
    for (int q = 0; q < 2; q++) {
      *(uint4*)&As[(q * 64 + row) * 32 + cg8] =
          *(const uint4*)&Ap[(size_t)(q * 64 + row) * DD + k0 + cg8];
      *(uint4*)&Bs[(q * 64 + row) * 32 + cg8] =
          *(const uint4*)&Wp[(size_t)(q * 64 + row) * DD + k0 + cg8];
    }
#endif
    __syncthreads();
    short8 af[4], bfr[4];
    #pragma unroll
    for (int i = 0; i < 4; i++)
      af[i] = *(short8*)&As[(64 * wm + 16 * i + frow) * 32 + fq8];
    #pragma unroll
    for (int j = 0; j < 4; j++)
      bfr[j] = *(short8*)&Bs[(64 * wn + 16 * j + frow) * 32 + fq8];
    #pragma unroll
    for (int i = 0; i < 4; i++)
      #pragma unroll
      for (int j = 0; j < 4; j++)
        acc[i][j] = __builtin_amdgcn_mfma_f32_16x16x32_bf16(af[i], bfr[j], acc[i][j], 0, 0, 0);
    __syncthreads();
  }
  const float* asc = ascale + (size_t)z * M_ROWS + m0;
  float wsc = wscale[proj];
  int col = lane & 15, rg = lane >> 4;
  #pragma unroll
  for (int i = 0; i < 4; i++) {
    #pragma unroll
    for (int r = 0; r < 4; r++) {
      int mm = 64 * wm + 16 * i + rg * 4 + r;
      float s = asc[mm] * wsc;
      #pragma unroll
      for (int j = 0; j < 4; j++) {
        int nn = 64 * wn + 16 * j + col;
        outF[((size_t)z * M_ROWS + m0 + mm) * DD + (n0 + nn)] = acc[i][j][r] * s;
      }
    }
  }
}

// ---- K5: per-chunk injection  inj[s,o] = sum_c w^{63-c} k[c,s] v[c,o] ----
__global__ __launch_bounds__(256) void k_inj(const float* __restrict__ rkvg,
                                             const float* __restrict__ log_decay,
                                             float* __restrict__ states) {
  __shared__ float ksh[CH * SS], vsh[CH * SS];
  int blk = blockIdx.x, tid = threadIdx.x;
  int n = blk & (NC - 1), h = (blk >> 5) & (HH - 1), b = blk >> 9;
  size_t rowbase = ((size_t)b * TT + n * CH) * DD + h * SS;
  const float* Kp = rkvg + (size_t)1 * M_ROWS * DD + rowbase;
  const float* Vp = rkvg + (size_t)2 * M_ROWS * DD + rowbase;
  for (int idx = tid; idx < CH * SS; idx += 256) {
    int c = idx >> 6, s2 = idx & 63;
    ksh[idx] = Kp[(size_t)c * DD + s2];
    vsh[idx] = Vp[(size_t)c * DD + s2];
  }
  int o = tid & 63, sg = tid >> 6;
  float wv[16], acc[16];
  #pragma unroll
  for (int j = 0; j < 16; j++) {
    int s2 = sg * 16 + j;
    float e = expf(log_decay[h * SS + s2]);
    wv[j] = expf(-e); acc[j] = 0.f;
  }
  __syncthreads();
  for (int c = 0; c < CH; c++) {
    float vvv = vsh[c * SS + o];
    #pragma unroll
    for (int j = 0; j < 16; j++)
      acc[j] = wv[j] * acc[j] + ksh[c * SS + sg * 16 + j] * vvv;
  }
  float* st = states + (size_t)blk * SS * SS;
  #pragma unroll
  for (int j = 0; j < 16; j++) st[(size_t)(sg * 16 + j) * SS + o] = acc[j];
}

// ---- K6: in-place scan over chunks ----
__global__ __launch_bounds__(256) void k_scan(const float* __restrict__ log_decay,
                                              float* __restrict__ states) {
  int bh = blockIdx.x, tid = threadIdx.x;
  int h = bh & (HH - 1);
  int o = tid & 63, sg = tid >> 6;
  float wC[16], cur[16];
  #pragma unroll
  for (int j = 0; j < 16; j++) {
    int s2 = sg * 16 + j;
    float e = expf(log_decay[h * SS + s2]);
    wC[j] = expf(-64.f * e);
    cur[j] = 0.f;
  }
  float* base = states + (size_t)bh * NC * SS * SS;
  for (int n = 0; n < NC; n++) {
    float* p = base + (size_t)n * SS * SS;
    #pragma unroll
    for (int j = 0; j < 16; j++) {
      size_t ii = (size_t)(sg * 16 + j) * SS + o;
      float inj = p[ii];
      p[ii] = cur[j];
      cur[j] = wC[j] * cur[j] + inj;
    }
  }
}

// ---- K7 v5: single-backward-pass WKV. Wave sg owns s-slice [16sg,+16).
// Cross-chunk term folded into the backward loop via pw[j]=w^{t+1} maintained
// DESCENDING with winv; per-tile write+tree-reduce (no atomics) straight to
// global Y (no yacc). LDS 40.5 KB -> 3 blocks/CU. ~18 barriers. ----
__global__ __launch_bounds__(256) void k_wkv_y(const float* __restrict__ rkvg,
                                               const float* __restrict__ log_decay,
                                               const float* __restrict__ u,
                                               const float* __restrict__ states,
                                               float* __restrict__ Y) {
  __shared__ float rsh[CH * SS], ksh[CH * SS];   // 32 KB
  __shared__ float part[8 * 4 * SS];             // 8 KB
  __shared__ float betash[CH], eush[SS];
  int blk = blockIdx.x, tid = threadIdx.x;
  int n = blk & (NC - 1), h = (blk >> 5) & (HH - 1), b = blk >> 9;
  size_t rowbase = ((size_t)b * TT + n * CH) * DD + h * SS;
  const float* Rp = rkvg + rowbase;
  const float* Kp = rkvg + (size_t)1 * M_ROWS * DD + rowbase;
  const float* Vp = rkvg + (size_t)2 * M_ROWS * DD + rowbase;
  for (int idx = tid; idx < CH * SS; idx += 256) {
    int c = idx >> 6, s2 = idx & 63;
    rsh[idx] = Rp[(size_t)c * DD + s2];
    ksh[idx] = Kp[(size_t)c * DD + s2];
  }
  if (tid < SS) eush[tid] = expf(u[h * SS + tid]);
  __syncthreads();
  // beta: 4 threads per t, 16 s each, t-rotated addressing (2-way banks),
  // 2-step shfl fold within the 4 adjacent lanes.
  {
    int t = tid >> 2, sq = tid & 3;
    float s = 0.f;
    #pragma unroll
    for (int q = 0; q < 16; q++) {
      int s2 = sq * 16 + ((q + t) & 15);
      s += rsh[t * SS + s2] * ksh[t * SS + s2] * eush[s2];
    }
    s += __shfl_xor(s, 1);
    s += __shfl_xor(s, 2);
    if (sq == 0) betash[t] = s;
  }
  __syncthreads();

  int o = tid & 63, sg = tid >> 6, S0 = sg * 16;
  float wv[16], winv[16], pw[16], st[16], a[16];
  const float* stp = states + (size_t)blk * SS * SS;
  #pragma unroll
  for (int j = 0; j < 16; j++) {
    float e = expf(log_decay[h * SS + S0 + j]);
    wv[j] = expf(-e);
    winv[j] = 1.f / wv[j];
    pw[j] = expf(-64.f * e);                  // w^{64}, exact start (t=63)
    st[j] = stp[(size_t)(S0 + j) * SS + o];
    a[j] = 0.f;
  }
  float* Yb = Y + ((size_t)b * TT + n * CH) * DD + h * SS;
  for (int ti = 7; ti >= 0; ti--) {
    float v8[8];
    #pragma unroll
    for (int tt = 0; tt < 8; tt++)
      v8[tt] = Vp[(size_t)(ti * 8 + tt) * DD + o];
    float p8[8];
    #pragma unroll
    for (int tt = 7; tt >= 0; tt--) {
      int t = ti * 8 + tt;
      float v = v8[tt];
      float acc0 = 0.f, acc1 = 0.f;
      #pragma unroll
      for (int q = 0; q < 4; q++) {
        float4 k4 = *(const float4*)&ksh[t * SS + S0 + q * 4];
        float4 r4 = *(const float4*)&rsh[t * SS + S0 + q * 4];
        float kk[4] = {k4.x, k4.y, k4.z, k4.w};
        float rr[4] = {r4.x, r4.y, r4.z, r4.w};
        #pragma unroll
        for (int e = 0; e < 4; e++) {
          int j = q * 4 + e;
          a[j] = fmaf(wv[j], a[j], kk[e] * v);          // suffix scan
          float bterm = fmaf(pw[j], st[j], a[j]);       // + w^{t+1} state
          if (q < 2) acc0 = fmaf(rr[e], bterm, acc0);
          else       acc1 = fmaf(rr[e], bterm, acc1);
          pw[j] *= winv[j];                              // w^{t+1} -> w^{t}
        }
      }
      float p = acc0 + acc1;
      if (sg == 0) p = fmaf(betash[t], v, p);
      p8[tt] = p;
    }
    #pragma unroll
    for (int tt = 0; tt < 8; tt++) part[tt * 256 + sg * 64 + o] = p8[tt];
    __syncthreads();
    #pragma unroll
    for (int rep = 0; rep < 2; rep++) {
      int e = tid + rep * 256;                 // (tt, o2)
      int tt = e >> 6, o2 = e & 63;
      float s = part[tt * 256 + o2] + part[tt * 256 + 64 + o2]
              + part[tt * 256 + 128 + o2] + part[tt * 256 + 192 + o2];
      Yb[(size_t)(ti * 8 + tt) * DD + o2] = s;
    }
    __syncthreads();
  }
}

// ---- K8: GroupNorm + silu(g) + LayerNorm + act-quant ----
__global__ __launch_bounds__(256) void k_post(const float* __restrict__ Y,
                                              const float* __restrict__ G,
                                              const float* __restrict__ gn_g,
                                              const float* __restrict__ gn_b,
                                              const float* __restrict__ lg,
                                              const float* __restrict__ lb,
                                              bf16* __restrict__ xq4,
                                              float* __restrict__ ascale4) {
  __shared__ float red[256];
  __shared__ float ysh[DD];
  __shared__ float gmean[HH], grstd[HH];
  int m = blockIdx.x, tid = threadIdx.x;
  const float* Yr = Y + (size_t)m * DD;
  const float* Gr = G + (size_t)m * DD;
  #pragma unroll
  for (int j = 0; j < 4; j++) { int d = tid + j * 256; ysh[d] = Yr[d]; }
  __syncthreads();
  if (tid < HH) {
    float s = 0.f;
    for (int q2 = 0; q2 < SS; q2++) s += ysh[tid * SS + ((q2 + tid * 4) & 63)];
    float mn = s * (1.f / SS);
    float v2 = 0.f;
    for (int q2 = 0; q2 < SS; q2++) {
      float dv = ysh[tid * SS + ((q2 + tid * 4) & 63)] - mn; v2 += dv * dv;
    }
    gmean[tid] = mn;
    grstd[tid] = 1.f / sqrtf(v2 * (1.f / SS) + 1e-5f);
  }
  __syncthreads();
  float z[4];
  #pragma unroll
  for (int j = 0; j < 4; j++) {
    int d = tid + j * 256; int hh = d >> 6;
    float yn = (ysh[d] - gmean[hh]) * grstd[hh] * gn_g[d] + gn_b[d];
    float gv = Gr[d];
    z[j] = yn * (gv / (1.f + expf(-gv)));            // silu
  }
  float mean = block_sum(z[0] + z[1] + z[2] + z[3], red) * (1.f / DD);
  float var = 0.f;
  #pragma unroll
  for (int j = 0; j < 4; j++) { float dv = z[j] - mean; var += dv * dv; }
  var = block_sum(var, red) * (1.f / DD);
  float rstd = 1.f / sqrtf(var + 1e-5f);
  float ln[4]; float aabs = 0.f;
  #pragma unroll
  for (int j = 0; j < 4; j++) {
    int d = tid + j * 256;
    ln[j] = (z[j] - mean) * rstd * lg[d] + lb[d];
    aabs += fabsf(ln[j]);
  }
  float meanabs = block_sum(aabs, red) * (1.f / DD);
  float scale = fmaxf(meanabs, 1e-8f) * 2.5f * (1.f / 127.f);
  #pragma unroll
  for (int j = 0; j < 4; j++) {
    int d = tid + j * 256;
    xq4[(size_t)m * DD + d] =
        __float2bfloat16(rintf(fminf(fmaxf(ln[j] / scale, -127.f), 127.f)));
  }
  if (tid == 0) ascale4[m] = scale;
}

extern "C" void kernel_launch(void* const* d_in, const int* in_sizes, int n_in,
                              void* d_out, int out_size, void* d_ws, size_t ws_size,
                              hipStream_t stream) {
  // ALL inputs are float32 (verified R4); output float32.
  const float* x         = (const float*)d_in[0];
  const float* mu_r      = (const float*)d_in[1];
  const float* mu_k      = (const float*)d_in[2];
  const float* mu_v      = (const float*)d_in[3];
  const float* mu_g      = (const float*)d_in[4];
  const float* log_decay = (const float*)d_in[5];
  const float* u         = (const float*)d_in[6];
  const float* proj_w    = (const float*)d_in[7];
  const float* ln_g      = (const float*)d_in[8];
  const float* ln_b      = (const float*)d_in[9];
  const float* gn_g      = (const float*)d_in[10];
  const float* gn_b      = (const float*)d_in[11];
  float* out = (float*)d_out;

  // ---- workspace layout, ~234 MiB total; U region (64 MB) time-multiplexed ----
  char* p = (char*)d_ws;
  float*  wscale = (float*)p;  p += 256;                         // 5 f32
  double* wpart  = (double*)p; p += 4096;                        // 5*64 f64
  bf16*   wq     = (bf16*)p;   p += (size_t)5 * DD * DD * 2;     // 10 MB
  float*  ascale = (float*)p;  p += (size_t)5 * M_ROWS * 4;      // 160 KB
  char*   U      = p;          p += (size_t)4 * M_ROWS * DD * 2; // 64 MB
  bf16*   xq     = (bf16*)U;
  float*  Y      = (float*)U;
  bf16*   xq4    = (bf16*)(U + (size_t)M_ROWS * DD * 4);         // U + 32 MB
  float*  rkvg   = (float*)p;  p += (size_t)4 * M_ROWS * DD * 4; // 128 MB
  float*  states = (float*)p;  p += (size_t)BB * HH * NC * SS * SS * 4; // 32 MB

  hipLaunchKernelGGL(k_wscale_part, dim3(5, 64), dim3(256), 0, stream, proj_w, wpart);
  hipLaunchKernelGGL(k_wscale_fin, dim3(5), dim3(64), 0, stream, wpart, wscale);
  hipLaunchKernelGGL(k_wquant, dim3((5 * DD * DD) / 256), dim3(256), 0, stream,
                     proj_w, wscale, wq);
  hipLaunchKernelGGL(k_prep_quant, dim3(M_ROWS, 4), dim3(256), 0, stream,
                     x, mu_r, mu_k, mu_v, mu_g, ln_g, ln_b, xq, ascale);
  hipLaunchKernelGGL(k_gemm, dim3(M_ROWS / 128, DD / 128, 4), dim3(256), 0,
                     stream, xq, wq, ascale, wscale, 0, rkvg);
  hipLaunchKernelGGL(k_inj, dim3(BB * HH * NC), dim3(256), 0, stream,
                     rkvg, log_decay, states);
  hipLaunchKernelGGL(k_scan, dim3(BB * HH), dim3(256), 0, stream, log_decay, states);
  hipLaunchKernelGGL(k_wkv_y, dim3(BB * HH * NC), dim3(256), 0, stream,
                     rkvg, log_decay, u, states, Y);
  hipLaunchKernelGGL(k_post, dim3(M_ROWS), dim3(256), 0, stream,
                     Y, rkvg + (size_t)3 * M_ROWS * DD, gn_g, gn_b,
                     ln_g + 4 * DD, ln_b + 4 * DD,
                     xq4, ascale + 4 * M_ROWS);
  hipLaunchKernelGGL(k_gemm, dim3(M_ROWS / 128, DD / 128, 1), dim3(256), 0,
                     stream, xq4, wq,
                     ascale + 4 * M_ROWS, wscale, 4, out);
}

// Round 10
// 462.123 us; speedup vs baseline: 1.7015x; 1.0552x over previous
//
#include <hip/hip_runtime.h>
#include <hip/hip_bf16.h>

// Problem constants
#define BB 4
#define TT 2048
#define DD 1024
#define HH 16
#define SS 64
#define CH 64
#define NC (TT/CH)        // 32
#define M_ROWS (BB*TT)    // 8192

typedef __hip_bfloat16 bf16;
using short8 = __attribute__((ext_vector_type(8))) short;   // 8 bf16 (4 VGPRs)
using f32x4  = __attribute__((ext_vector_type(4))) float;

static __device__ __forceinline__ float b2f(bf16 v) { return __bfloat162float(v); }

#if defined(__has_builtin)
#if __has_builtin(__builtin_amdgcn_global_load_lds)
#define HAVE_GLL 1
#endif
#endif

#ifdef HAVE_GLL
// async global->LDS, 16 B per lane; LDS dst is wave-uniform base + lane*16
static __device__ __forceinline__ void gload16(const void* g, void* l) {
  __builtin_amdgcn_global_load_lds(
      (const __attribute__((address_space(1))) void*)g,
      (__attribute__((address_space(3))) void*)l, 16, 0, 0);
}
#endif

// ---- wave-wide sum (64 lanes, deterministic butterfly) ----
static __device__ __forceinline__ float wave_sum(float v) {
  #pragma unroll
  for (int d = 1; d < 64; d <<= 1) v += __shfl_xor(v, d);
  return v;
}

// ---- block sum over 256 threads: shfl + 4-slot LDS, ONE barrier.
// Each call site must pass its own 4-float slot (no reuse hazard). ----
static __device__ __forceinline__ float block_sum4(float v, float* slot, int tid) {
  float w = wave_sum(v);
  if ((tid & 63) == 0) slot[tid >> 6] = w;
  __syncthreads();
  return slot[0] + slot[1] + slot[2] + slot[3];
}

// ---- K1a: weight-scale partials. grid (5,64) ----
__global__ __launch_bounds__(256) void k_wscale_part(const float* __restrict__ w,
                                                     double* __restrict__ wpart) {
  __shared__ double red[256];
  int i = blockIdx.x, b = blockIdx.y, tid = threadIdx.x;
  const float* base = w + (size_t)i * DD * DD + (size_t)b * 16384;
  double s = 0.0;
  #pragma unroll
  for (int j = 0; j < 64; j++) s += (double)fabsf(base[tid + j * 256]);
  red[tid] = s; __syncthreads();
  for (int o = 128; o > 0; o >>= 1) {
    if (tid < o) red[tid] += red[tid + o];
    __syncthreads();
  }
  if (tid == 0) wpart[i * 64 + b] = red[0];
}

// ---- K1b: fold 64 partials per matrix in fixed order ----
__global__ __launch_bounds__(64) void k_wscale_fin(const double* __restrict__ wpart,
                                                   float* __restrict__ wscale) {
  int i = blockIdx.x;
  if (threadIdx.x == 0) {
    double s = 0.0;
    for (int b = 0; b < 64; b++) s += wpart[i * 64 + b];
    wscale[i] = fmaxf((float)(s * (1.0 / (DD * DD))), 1e-8f);
  }
}

// ---- K2: ternary weight quant, stored as exact bf16 {-1,0,1} ----
__global__ __launch_bounds__(256) void k_wquant(const float* __restrict__ w,
                                                const float* __restrict__ wscale,
                                                bf16* __restrict__ wq) {
  int idx = blockIdx.x * 256 + threadIdx.x;   // < 5*1024*1024
  int i = idx >> 20;
  float ws = wscale[i];
  float wn = w[idx] / ws;
  wn = fminf(fmaxf(wn, -1.f), 1.f);
  wq[idx] = __float2bfloat16(rintf(wn));
}

// ---- K3 v2: FUSED token-shift + LN + act-quant for all 4 projections.
// One block per row m; x read once; 12 single-barrier reductions. ----
__global__ __launch_bounds__(256) void k_prep_quant(
    const float* __restrict__ x, const float* __restrict__ mu_r,
    const float* __restrict__ mu_k, const float* __restrict__ mu_v,
    const float* __restrict__ mu_g, const float* __restrict__ ln_g,
    const float* __restrict__ ln_b, bf16* __restrict__ xq,
    float* __restrict__ ascale) {
  __shared__ float slots[12 * 4];
  int m = blockIdx.x, tid = threadIdx.x;
  int t = m & (TT - 1);
  const float* xr = x + (size_t)m * DD;
  float xv[4], xs[4];
  #pragma unroll
  for (int j = 0; j < 4; j++) {
    int d = tid + j * 256;
    xv[j] = xr[d];
    xs[j] = (t > 0) ? xr[d - DD] : 0.f;
  }
  const float* mus[4] = {mu_r, mu_k, mu_v, mu_g};
  #pragma unroll 1
  for (int i = 0; i < 4; i++) {
    const float* mu = mus[i];
    const float* lg = ln_g + i * DD;
    const float* lb = ln_b + i * DD;
    float inp[4];
    #pragma unroll
    for (int j = 0; j < 4; j++) {
      int d = tid + j * 256;
      inp[j] = xv[j] + (xs[j] - xv[j]) * mu[d];
    }
    float mean = block_sum4(inp[0] + inp[1] + inp[2] + inp[3],
                            &slots[(i * 3 + 0) * 4], tid) * (1.f / DD);
    float var = 0.f;
    #pragma unroll
    for (int j = 0; j < 4; j++) { float dv = inp[j] - mean; var += dv * dv; }
    var = block_sum4(var, &slots[(i * 3 + 1) * 4], tid) * (1.f / DD);
    float rstd = 1.f / sqrtf(var + 1e-5f);
    float ln[4]; float aabs = 0.f;
    #pragma unroll
    for (int j = 0; j < 4; j++) {
      int d = tid + j * 256;
      ln[j] = (inp[j] - mean) * rstd * lg[d] + lb[d];
      aabs += fabsf(ln[j]);
    }
    float meanabs = block_sum4(aabs, &slots[(i * 3 + 2) * 4], tid) * (1.f / DD);
    float scale = fmaxf(meanabs, 1e-8f) * 2.5f * (1.f / 127.f);
    bf16* xo = xq + ((size_t)i * M_ROWS + m) * DD;
    #pragma unroll
    for (int j = 0; j < 4; j++) {
      int d = tid + j * 256;
      float q = rintf(fminf(fmaxf(ln[j] / scale, -127.f), 127.f));
      xo[d] = __float2bfloat16(q);            // exact: |int| <= 127
    }
    if (tid == 0) ascale[i * M_ROWS + m] = scale;
  }
}

// ---- K4/K9: bf16 MFMA GEMM, 128x128 tile + async global->LDS (unchanged R8/R9) ----
__global__ __launch_bounds__(256) void k_gemm(
    const bf16* __restrict__ Axq, const bf16* __restrict__ Wq,
    const float* __restrict__ ascale, const float* __restrict__ wscale,
    int projbase, float* __restrict__ outF) {
  __shared__ short As[128 * 32];
  __shared__ short Bs[128 * 32];
  int tid = threadIdx.x;
  int wvid = tid >> 6, lane = tid & 63;
  int wm = wvid >> 1, wn = wvid & 1;
  int m0 = blockIdx.x * 128, n0 = blockIdx.y * 128;
  int z = blockIdx.z;
  int proj = projbase + z;
  const bf16* Ap = Axq + ((size_t)z * M_ROWS + m0) * DD;
  const bf16* Wp = Wq + ((size_t)proj * DD + n0) * DD;
  f32x4 acc[4][4];
  #pragma unroll
  for (int i = 0; i < 4; i++)
    #pragma unroll
    for (int j = 0; j < 4; j++) acc[i][j] = (f32x4){0.f, 0.f, 0.f, 0.f};
  int row = tid >> 2, cg8 = (tid & 3) * 8;    // staging: 16B/thread/issue
  int frow = lane & 15, fq8 = (lane >> 4) * 8;
  for (int k0 = 0; k0 < DD; k0 += 32) {
#ifdef HAVE_GLL
    #pragma unroll
    for (int q = 0; q < 2; q++) {
      gload16(&Ap[(size_t)(q * 64 + row) * DD + k0 + cg8], &As[tid * 8 + q * 2048]);
      gload16(&Wp[(size_t)(q * 64 + row) * DD + k0 + cg8], &Bs[tid * 8 + q * 2048]);
    }
#else
    #pragma unroll
    for (int q = 0; q < 2; q++) {
      *(uint4*)&As[(q * 64 + row) * 32 + cg8] =
          *(const uint4*)&Ap[(size_t)(q * 64 + row) * DD + k0 + cg8];
      *(uint4*)&Bs[(q * 64 + row) * 32 + cg8] =
          *(const uint4*)&Wp[(size_t)(q * 64 + row) * DD + k0 + cg8];
    }
#endif
    __syncthreads();
    short8 af[4], bfr[4];
    #pragma unroll
    for (int i = 0; i < 4; i++)
      af[i] = *(short8*)&As[(64 * wm + 16 * i + frow) * 32 + fq8];
    #pragma unroll
    for (int j = 0; j < 4; j++)
      bfr[j] = *(short8*)&Bs[(64 * wn + 16 * j + frow) * 32 + fq8];
    #pragma unroll
    for (int i = 0; i < 4; i++)
      #pragma unroll
      for (int j = 0; j < 4; j++)
        acc[i][j] = __builtin_amdgcn_mfma_f32_16x16x32_bf16(af[i], bfr[j], acc[i][j], 0, 0, 0);
    __syncthreads();
  }
  const float* asc = ascale + (size_t)z * M_ROWS + m0;
  float wsc = wscale[proj];
  int col = lane & 15, rg = lane >> 4;
  #pragma unroll
  for (int i = 0; i < 4; i++) {
    #pragma unroll
    for (int r = 0; r < 4; r++) {
      int mm = 64 * wm + 16 * i + rg * 4 + r;
      float s = asc[mm] * wsc;
      #pragma unroll
      for (int j = 0; j < 4; j++) {
        int nn = 64 * wn + 16 * j + col;
        outF[((size_t)z * M_ROWS + m0 + mm) * DD + (n0 + nn)] = acc[i][j][r] * s;
      }
    }
  }
}

// ---- K5 v2: per-chunk injection; k in LDS (16 KB), v streamed from global ----
__global__ __launch_bounds__(256) void k_inj(const float* __restrict__ rkvg,
                                             const float* __restrict__ log_decay,
                                             float* __restrict__ states) {
  __shared__ float ksh[CH * SS];
  int blk = blockIdx.x, tid = threadIdx.x;
  int n = blk & (NC - 1), h = (blk >> 5) & (HH - 1), b = blk >> 9;
  size_t rowbase = ((size_t)b * TT + n * CH) * DD + h * SS;
  const float* Kp = rkvg + (size_t)1 * M_ROWS * DD + rowbase;
  const float* Vp = rkvg + (size_t)2 * M_ROWS * DD + rowbase;
  for (int idx = tid; idx < CH * SS; idx += 256) {
    int c = idx >> 6, s2 = idx & 63;
    ksh[idx] = Kp[(size_t)c * DD + s2];
  }
  int o = tid & 63, sg = tid >> 6, S0 = sg * 16;
  float wv[16], acc[16];
  #pragma unroll
  for (int j = 0; j < 16; j++) {
    float e = expf(log_decay[h * SS + S0 + j]);
    wv[j] = expf(-e); acc[j] = 0.f;
  }
  __syncthreads();
  for (int ti = 0; ti < 8; ti++) {
    float v8[8];
    #pragma unroll
    for (int tt = 0; tt < 8; tt++)
      v8[tt] = Vp[(size_t)(ti * 8 + tt) * DD + o];
    #pragma unroll
    for (int tt = 0; tt < 8; tt++) {
      int c = ti * 8 + tt;
      float v = v8[tt];
      #pragma unroll
      for (int q = 0; q < 4; q++) {
        float4 k4 = *(const float4*)&ksh[c * SS + S0 + q * 4];
        float kk[4] = {k4.x, k4.y, k4.z, k4.w};
        #pragma unroll
        for (int e = 0; e < 4; e++) {
          int j = q * 4 + e;
          acc[j] = fmaf(wv[j], acc[j], kk[e] * v);
        }
      }
    }
  }
  float* st = states + (size_t)blk * SS * SS;
  #pragma unroll
  for (int j = 0; j < 16; j++) st[(size_t)(S0 + j) * SS + o] = acc[j];
}

// ---- K6 v2: PARALLEL scan — one thread per (b,h,s,o) element. grid 1024. ----
__global__ __launch_bounds__(256) void k_scan(const float* __restrict__ log_decay,
                                              float* __restrict__ states) {
  int blk = blockIdx.x;                 // bh*16 + sb
  int bh = blk >> 4, sb = blk & 15;
  int h = bh & (HH - 1);
  int tid = threadIdx.x;
  int js = tid >> 6, o = tid & 63;
  int s = sb * 4 + js;
  float wC = expf(-64.f * expf(log_decay[h * SS + s]));
  float cur = 0.f;
  float* base = states + (size_t)bh * NC * SS * SS + (size_t)s * SS + o;
  for (int n = 0; n < NC; n++) {
    float* p = base + (size_t)n * SS * SS;
    float inj = *p;
    *p = cur;
    cur = fmaf(wC, cur, inj);
  }
}

// ---- K7 v5: single-backward-pass WKV (unchanged from R9) ----
__global__ __launch_bounds__(256) void k_wkv_y(const float* __restrict__ rkvg,
                                               const float* __restrict__ log_decay,
                                               const float* __restrict__ u,
                                               const float* __restrict__ states,
                                               float* __restrict__ Y) {
  __shared__ float rsh[CH * SS], ksh[CH * SS];   // 32 KB
  __shared__ float part[8 * 4 * SS];             // 8 KB
  __shared__ float betash[CH], eush[SS];
  int blk = blockIdx.x, tid = threadIdx.x;
  int n = blk & (NC - 1), h = (blk >> 5) & (HH - 1), b = blk >> 9;
  size_t rowbase = ((size_t)b * TT + n * CH) * DD + h * SS;
  const float* Rp = rkvg + rowbase;
  const float* Kp = rkvg + (size_t)1 * M_ROWS * DD + rowbase;
  const float* Vp = rkvg + (size_t)2 * M_ROWS * DD + rowbase;
  for (int idx = tid; idx < CH * SS; idx += 256) {
    int c = idx >> 6, s2 = idx & 63;
    rsh[idx] = Rp[(size_t)c * DD + s2];
    ksh[idx] = Kp[(size_t)c * DD + s2];
  }
  if (tid < SS) eush[tid] = expf(u[h * SS + tid]);
  __syncthreads();
  {
    int t = tid >> 2, sq = tid & 3;
    float s = 0.f;
    #pragma unroll
    for (int q = 0; q < 16; q++) {
      int s2 = sq * 16 + ((q + t) & 15);
      s += rsh[t * SS + s2] * ksh[t * SS + s2] * eush[s2];
    }
    s += __shfl_xor(s, 1);
    s += __shfl_xor(s, 2);
    if (sq == 0) betash[t] = s;
  }
  __syncthreads();

  int o = tid & 63, sg = tid >> 6, S0 = sg * 16;
  float wv[16], winv[16], pw[16], st[16], a[16];
  const float* stp = states + (size_t)blk * SS * SS;
  #pragma unroll
  for (int j = 0; j < 16; j++) {
    float e = expf(log_decay[h * SS + S0 + j]);
    wv[j] = expf(-e);
    winv[j] = 1.f / wv[j];
    pw[j] = expf(-64.f * e);                  // w^{64}, exact start (t=63)
    st[j] = stp[(size_t)(S0 + j) * SS + o];
    a[j] = 0.f;
  }
  float* Yb = Y + ((size_t)b * TT + n * CH) * DD + h * SS;
  for (int ti = 7; ti >= 0; ti--) {
    float v8[8];
    #pragma unroll
    for (int tt = 0; tt < 8; tt++)
      v8[tt] = Vp[(size_t)(ti * 8 + tt) * DD + o];
    float p8[8];
    #pragma unroll
    for (int tt = 7; tt >= 0; tt--) {
      int t = ti * 8 + tt;
      float v = v8[tt];
      float acc0 = 0.f, acc1 = 0.f;
      #pragma unroll
      for (int q = 0; q < 4; q++) {
        float4 k4 = *(const float4*)&ksh[t * SS + S0 + q * 4];
        float4 r4 = *(const float4*)&rsh[t * SS + S0 + q * 4];
        float kk[4] = {k4.x, k4.y, k4.z, k4.w};
        float rr[4] = {r4.x, r4.y, r4.z, r4.w};
        #pragma unroll
        for (int e = 0; e < 4; e++) {
          int j = q * 4 + e;
          a[j] = fmaf(wv[j], a[j], kk[e] * v);          // suffix scan
          float bterm = fmaf(pw[j], st[j], a[j]);       // + w^{t+1} state
          if (q < 2) acc0 = fmaf(rr[e], bterm, acc0);
          else       acc1 = fmaf(rr[e], bterm, acc1);
          pw[j] *= winv[j];                              // w^{t+1} -> w^{t}
        }
      }
      float p = acc0 + acc1;
      if (sg == 0) p = fmaf(betash[t], v, p);
      p8[tt] = p;
    }
    #pragma unroll
    for (int tt = 0; tt < 8; tt++) part[tt * 256 + sg * 64 + o] = p8[tt];
    __syncthreads();
    #pragma unroll
    for (int rep = 0; rep < 2; rep++) {
      int e = tid + rep * 256;                 // (tt, o2)
      int tt = e >> 6, o2 = e & 63;
      float s = part[tt * 256 + o2] + part[tt * 256 + 64 + o2]
              + part[tt * 256 + 128 + o2] + part[tt * 256 + 192 + o2];
      Yb[(size_t)(ti * 8 + tt) * DD + o2] = s;
    }
    __syncthreads();
  }
}

// ---- K8 v2: GroupNorm (16-lane shfl stats) + silu(g) + LN + act-quant ----
__global__ __launch_bounds__(256) void k_post(const float* __restrict__ Y,
                                              const float* __restrict__ G,
                                              const float* __restrict__ gn_g,
                                              const float* __restrict__ gn_b,
                                              const float* __restrict__ lg,
                                              const float* __restrict__ lb,
                                              bf16* __restrict__ xq4,
                                              float* __restrict__ ascale4) {
  __shared__ float slots[3 * 4];
  __shared__ float ysh[DD];
  __shared__ float gmean[HH], grstd[HH];
  int m = blockIdx.x, tid = threadIdx.x;
  const float* Yr = Y + (size_t)m * DD;
  const float* Gr = G + (size_t)m * DD;
  #pragma unroll
  for (int j = 0; j < 4; j++) { int d = tid + j * 256; ysh[d] = Yr[d]; }
  __syncthreads();
  // GN stats: 16 threads/head, 4 elems each, shfl fold within 16-lane groups
  {
    int h2 = tid >> 4, l16 = tid & 15;
    float y4[4];
    #pragma unroll
    for (int q = 0; q < 4; q++) y4[q] = ysh[h2 * 64 + q * 16 + l16];
    float s = y4[0] + y4[1] + y4[2] + y4[3];
    s += __shfl_xor(s, 1); s += __shfl_xor(s, 2);
    s += __shfl_xor(s, 4); s += __shfl_xor(s, 8);
    float mn = s * (1.f / SS);
    float v2 = 0.f;
    #pragma unroll
    for (int q = 0; q < 4; q++) { float dv = y4[q] - mn; v2 += dv * dv; }
    v2 += __shfl_xor(v2, 1); v2 += __shfl_xor(v2, 2);
    v2 += __shfl_xor(v2, 4); v2 += __shfl_xor(v2, 8);
    if (l16 == 0) {
      gmean[h2] = mn;
      grstd[h2] = 1.f / sqrtf(v2 * (1.f / SS) + 1e-5f);
    }
  }
  __syncthreads();
  float z[4];
  #pragma unroll
  for (int j = 0; j < 4; j++) {
    int d = tid + j * 256; int hh = d >> 6;
    float yn = (ysh[d] - gmean[hh]) * grstd[hh] * gn_g[d] + gn_b[d];
    float gv = Gr[d];
    z[j] = yn * (gv / (1.f + expf(-gv)));            // silu
  }
  float mean = block_sum4(z[0] + z[1] + z[2] + z[3], &slots[0], tid) * (1.f / DD);
  float var = 0.f;
  #pragma unroll
  for (int j = 0; j < 4; j++) { float dv = z[j] - mean; var += dv * dv; }
  var = block_sum4(var, &slots[4], tid) * (1.f / DD);
  float rstd = 1.f / sqrtf(var + 1e-5f);
  float ln[4]; float aabs = 0.f;
  #pragma unroll
  for (int j = 0; j < 4; j++) {
    int d = tid + j * 256;
    ln[j] = (z[j] - mean) * rstd * lg[d] + lb[d];
    aabs += fabsf(ln[j]);
  }
  float meanabs = block_sum4(aabs, &slots[8], tid) * (1.f / DD);
  float scale = fmaxf(meanabs, 1e-8f) * 2.5f * (1.f / 127.f);
  #pragma unroll
  for (int j = 0; j < 4; j++) {
    int d = tid + j * 256;
    xq4[(size_t)m * DD + d] =
        __float2bfloat16(rintf(fminf(fmaxf(ln[j] / scale, -127.f), 127.f)));
  }
  if (tid == 0) ascale4[m] = scale;
}

extern "C" void kernel_launch(void* const* d_in, const int* in_sizes, int n_in,
                              void* d_out, int out_size, void* d_ws, size_t ws_size,
                              hipStream_t stream) {
  // ALL inputs are float32 (verified R4); output float32.
  const float* x         = (const float*)d_in[0];
  const float* mu_r      = (const float*)d_in[1];
  const float* mu_k      = (const float*)d_in[2];
  const float* mu_v      = (const float*)d_in[3];
  const float* mu_g      = (const float*)d_in[4];
  const float* log_decay = (const float*)d_in[5];
  const float* u         = (const float*)d_in[6];
  const float* proj_w    = (const float*)d_in[7];
  const float* ln_g      = (const float*)d_in[8];
  const float* ln_b      = (const float*)d_in[9];
  const float* gn_g      = (const float*)d_in[10];
  const float* gn_b      = (const float*)d_in[11];
  float* out = (float*)d_out;

  // ---- workspace layout, ~234 MiB total; U region (64 MB) time-multiplexed ----
  char* p = (char*)d_ws;
  float*  wscale = (float*)p;  p += 256;                         // 5 f32
  double* wpart  = (double*)p; p += 4096;                        // 5*64 f64
  bf16*   wq     = (bf16*)p;   p += (size_t)5 * DD * DD * 2;     // 10 MB
  float*  ascale = (float*)p;  p += (size_t)5 * M_ROWS * 4;      // 160 KB
  char*   U      = p;          p += (size_t)4 * M_ROWS * DD * 2; // 64 MB
  bf16*   xq     = (bf16*)U;
  float*  Y      = (float*)U;
  bf16*   xq4    = (bf16*)(U + (size_t)M_ROWS * DD * 4);         // U + 32 MB
  float*  rkvg   = (float*)p;  p += (size_t)4 * M_ROWS * DD * 4; // 128 MB
  float*  states = (float*)p;  p += (size_t)BB * HH * NC * SS * SS * 4; // 32 MB

  hipLaunchKernelGGL(k_wscale_part, dim3(5, 64), dim3(256), 0, stream, proj_w, wpart);
  hipLaunchKernelGGL(k_wscale_fin, dim3(5), dim3(64), 0, stream, wpart, wscale);
  hipLaunchKernelGGL(k_wquant, dim3((5 * DD * DD) / 256), dim3(256), 0, stream,
                     proj_w, wscale, wq);
  hipLaunchKernelGGL(k_prep_quant, dim3(M_ROWS), dim3(256), 0, stream,
                     x, mu_r, mu_k, mu_v, mu_g, ln_g, ln_b, xq, ascale);
  hipLaunchKernelGGL(k_gemm, dim3(M_ROWS / 128, DD / 128, 4), dim3(256), 0,
                     stream, xq, wq, ascale, wscale, 0, rkvg);
  hipLaunchKernelGGL(k_inj, dim3(BB * HH * NC), dim3(256), 0, stream,
                     rkvg, log_decay, states);
  hipLaunchKernelGGL(k_scan, dim3(BB * HH * 16), dim3(256), 0, stream,
                     log_decay, states);
  hipLaunchKernelGGL(k_wkv_y, dim3(BB * HH * NC), dim3(256), 0, stream,
                     rkvg, log_decay, u, states, Y);
  hipLaunchKernelGGL(k_post, dim3(M_ROWS), dim3(256), 0, stream,
                     Y, rkvg + (size_t)3 * M_ROWS * DD, gn_g, gn_b,
                     ln_g + 4 * DD, ln_b + 4 * DD,
                     xq4, ascale + 4 * M_ROWS);
  hipLaunchKernelGGL(k_gemm, dim3(M_ROWS / 128, DD / 128, 1), dim3(256), 0,
                     stream, xq4, wq,
                     ascale + 4 * M_ROWS, wscale, 4, out);
}

// Round 11
// 397.540 us; speedup vs baseline: 1.9779x; 1.1625x over previous
//
#include <hip/hip_runtime.h>
#include <hip/hip_bf16.h>

// Problem constants
#define BB 4
#define TT 2048
#define DD 1024
#define HH 16
#define SS 64
#define CH 64
#define NC (TT/CH)        // 32
#define M_ROWS (BB*TT)    // 8192

typedef __hip_bfloat16 bf16;
using int4v = __attribute__((ext_vector_type(4))) int;

#if defined(__has_builtin)
#if __has_builtin(__builtin_amdgcn_global_load_lds)
#define HAVE_GLL 1
#endif
#if __has_builtin(__builtin_amdgcn_mfma_i32_16x16x64_i8)
#define HAVE_I8K64 1
#endif
#endif

#ifdef HAVE_GLL
// async global->LDS, 16 B per lane; LDS dst contiguous in lane order
static __device__ __forceinline__ void gload16(const void* g, void* l) {
  __builtin_amdgcn_global_load_lds(
      (const __attribute__((address_space(1))) void*)g,
      (__attribute__((address_space(3))) void*)l, 16, 0, 0);
}
#endif

// ---- wave-wide sum (64 lanes, deterministic butterfly) ----
static __device__ __forceinline__ float wave_sum(float v) {
  #pragma unroll
  for (int d = 1; d < 64; d <<= 1) v += __shfl_xor(v, d);
  return v;
}

// ---- block sum over 256 threads: shfl + 4-slot LDS, ONE barrier. ----
static __device__ __forceinline__ float block_sum4(float v, float* slot, int tid) {
  float w = wave_sum(v);
  if ((tid & 63) == 0) slot[tid >> 6] = w;
  __syncthreads();
  return slot[0] + slot[1] + slot[2] + slot[3];
}

static __device__ __forceinline__ int pack4(int a, int b, int c, int d) {
  return (a & 0xff) | ((b & 0xff) << 8) | ((c & 0xff) << 16) | ((d & 0xff) << 24);
}

// ---- K1a: weight-scale partials. grid (5,64) ----
__global__ __launch_bounds__(256) void k_wscale_part(const float* __restrict__ w,
                                                     double* __restrict__ wpart) {
  __shared__ double red[256];
  int i = blockIdx.x, b = blockIdx.y, tid = threadIdx.x;
  const float* base = w + (size_t)i * DD * DD + (size_t)b * 16384;
  double s = 0.0;
  #pragma unroll
  for (int j = 0; j < 64; j++) s += (double)fabsf(base[tid + j * 256]);
  red[tid] = s; __syncthreads();
  for (int o = 128; o > 0; o >>= 1) {
    if (tid < o) red[tid] += red[tid + o];
    __syncthreads();
  }
  if (tid == 0) wpart[i * 64 + b] = red[0];
}

// ---- K1b: fold 64 partials per matrix in fixed order ----
__global__ __launch_bounds__(64) void k_wscale_fin(const double* __restrict__ wpart,
                                                   float* __restrict__ wscale) {
  int i = blockIdx.x;
  if (threadIdx.x == 0) {
    double s = 0.0;
    for (int b = 0; b < 64; b++) s += wpart[i * 64 + b];
    wscale[i] = fmaxf((float)(s * (1.0 / (DD * DD))), 1e-8f);
  }
}

// ---- K2 v2: ternary weight quant -> int8 {-1,0,1}, packed int stores ----
__global__ __launch_bounds__(256) void k_wquant(const float* __restrict__ w,
                                                const float* __restrict__ wscale,
                                                char* __restrict__ wq) {
  int idx4 = (blockIdx.x * 256 + threadIdx.x) * 4;   // < 5*1024*1024
  int i = idx4 >> 20;
  float ws = wscale[i];
  float4 w4 = *(const float4*)&w[idx4];
  float vals[4] = {w4.x, w4.y, w4.z, w4.w};
  int q[4];
  #pragma unroll
  for (int j = 0; j < 4; j++) {
    float wn = fminf(fmaxf(vals[j] / ws, -1.f), 1.f);
    q[j] = (int)rintf(wn);
  }
  *(int*)&wq[idx4] = pack4(q[0], q[1], q[2], q[3]);
}

// ---- K3 v3: FUSED token-shift + LN + act-quant, int8 out, float4 loads.
// Thread owns d = tid*4 .. tid*4+3 (contiguous). ----
__global__ __launch_bounds__(256) void k_prep_quant(
    const float* __restrict__ x, const float* __restrict__ mu_r,
    const float* __restrict__ mu_k, const float* __restrict__ mu_v,
    const float* __restrict__ mu_g, const float* __restrict__ ln_g,
    const float* __restrict__ ln_b, char* __restrict__ xq,
    float* __restrict__ ascale) {
  __shared__ float slots[12 * 4];
  int m = blockIdx.x, tid = threadIdx.x;
  int t = m & (TT - 1);
  const float* xr = x + (size_t)m * DD;
  int d4 = tid * 4;
  float4 xv4 = *(const float4*)&xr[d4];
  float4 xs4 = (t > 0) ? *(const float4*)&xr[d4 - DD]
                       : (float4){0.f, 0.f, 0.f, 0.f};
  float xv[4] = {xv4.x, xv4.y, xv4.z, xv4.w};
  float xs[4] = {xs4.x, xs4.y, xs4.z, xs4.w};
  const float* mus[4] = {mu_r, mu_k, mu_v, mu_g};
  #pragma unroll 1
  for (int i = 0; i < 4; i++) {
    float4 mu4 = *(const float4*)&mus[i][d4];
    float mu[4] = {mu4.x, mu4.y, mu4.z, mu4.w};
    float inp[4];
    #pragma unroll
    for (int j = 0; j < 4; j++) inp[j] = xv[j] + (xs[j] - xv[j]) * mu[j];
    float mean = block_sum4(inp[0] + inp[1] + inp[2] + inp[3],
                            &slots[(i * 3 + 0) * 4], tid) * (1.f / DD);
    float var = 0.f;
    #pragma unroll
    for (int j = 0; j < 4; j++) { float dv = inp[j] - mean; var += dv * dv; }
    var = block_sum4(var, &slots[(i * 3 + 1) * 4], tid) * (1.f / DD);
    float rstd = 1.f / sqrtf(var + 1e-5f);
    float4 lg4 = *(const float4*)&ln_g[i * DD + d4];
    float4 lb4 = *(const float4*)&ln_b[i * DD + d4];
    float lg[4] = {lg4.x, lg4.y, lg4.z, lg4.w};
    float lb[4] = {lb4.x, lb4.y, lb4.z, lb4.w};
    float ln[4]; float aabs = 0.f;
    #pragma unroll
    for (int j = 0; j < 4; j++) {
      ln[j] = (inp[j] - mean) * rstd * lg[j] + lb[j];
      aabs += fabsf(ln[j]);
    }
    float meanabs = block_sum4(aabs, &slots[(i * 3 + 2) * 4], tid) * (1.f / DD);
    float scale = fmaxf(meanabs, 1e-8f) * 2.5f * (1.f / 127.f);
    int q[4];
    #pragma unroll
    for (int j = 0; j < 4; j++)
      q[j] = (int)rintf(fminf(fmaxf(ln[j] / scale, -127.f), 127.f));
    *(int*)&xq[((size_t)i * M_ROWS + m) * DD + d4] = pack4(q[0], q[1], q[2], q[3]);
    if (tid == 0) ascale[i * M_ROWS + m] = scale;
  }
}

// ---- K4/K9 v2: INT8 MFMA GEMM, 128x128 tile, BK=64, i32 exact accumulate.
// mfma_i32_16x16x64_i8 (2x K, 2x rate vs bf16); C/D layout dtype-independent.
// A-frag: lane holds 16 consecutive k-bytes at row (lane&15), k0+(lane>>4)*16. ----
__global__ __launch_bounds__(256) void k_gemm(
    const char* __restrict__ Axq, const char* __restrict__ Wq,
    const float* __restrict__ ascale, const float* __restrict__ wscale,
    int projbase, float* __restrict__ outF) {
  __shared__ __align__(16) char As[128 * 64];
  __shared__ __align__(16) char Bs[128 * 64];
  int tid = threadIdx.x;
  int wvid = tid >> 6, lane = tid & 63;
  int wm = wvid >> 1, wn = wvid & 1;
  int m0 = blockIdx.x * 128, n0 = blockIdx.y * 128;
  int z = blockIdx.z;
  int proj = projbase + z;
  const char* Ap = Axq + ((size_t)z * M_ROWS + m0) * DD;
  const char* Wp = Wq + ((size_t)proj * DD + n0) * DD;
  int4v acc[4][4];
  #pragma unroll
  for (int i = 0; i < 4; i++)
    #pragma unroll
    for (int j = 0; j < 4; j++) acc[i][j] = (int4v){0, 0, 0, 0};
  int row = tid >> 2, col16 = (tid & 3) * 16;   // staging: 16B/thread, 64 rows/pass
  int frow = lane & 15, fq16 = (lane >> 4) * 16;
  for (int k0 = 0; k0 < DD; k0 += 64) {
#ifdef HAVE_GLL
    #pragma unroll
    for (int q = 0; q < 2; q++) {
      gload16(&Ap[(size_t)(q * 64 + row) * DD + k0 + col16], &As[q * 4096 + tid * 16]);
      gload16(&Wp[(size_t)(q * 64 + row) * DD + k0 + col16], &Bs[q * 4096 + tid * 16]);
    }
#else
    #pragma unroll
    for (int q = 0; q < 2; q++) {
      *(uint4*)&As[(q * 64 + row) * 64 + col16] =
          *(const uint4*)&Ap[(size_t)(q * 64 + row) * DD + k0 + col16];
      *(uint4*)&Bs[(q * 64 + row) * 64 + col16] =
          *(const uint4*)&Wp[(size_t)(q * 64 + row) * DD + k0 + col16];
    }
#endif
    __syncthreads();
#ifdef HAVE_I8K64
    int4v af[4], bfr[4];
    #pragma unroll
    for (int i = 0; i < 4; i++)
      af[i] = *(const int4v*)&As[(64 * wm + 16 * i + frow) * 64 + fq16];
    #pragma unroll
    for (int j = 0; j < 4; j++)
      bfr[j] = *(const int4v*)&Bs[(64 * wn + 16 * j + frow) * 64 + fq16];
    #pragma unroll
    for (int i = 0; i < 4; i++)
      #pragma unroll
      for (int j = 0; j < 4; j++)
        acc[i][j] = __builtin_amdgcn_mfma_i32_16x16x64_i8(af[i], bfr[j], acc[i][j], 0, 0, 0);
#else
    // fallback: two K=32 i8 MFMAs (8 int8 = long per operand half)
    int fq8 = (lane >> 4) * 8;
    long afl[4][2], bfl[4][2];
    #pragma unroll
    for (int i = 0; i < 4; i++)
      #pragma unroll
      for (int h = 0; h < 2; h++)
        afl[i][h] = *(const long*)&As[(64 * wm + 16 * i + frow) * 64 + h * 32 + fq8];
    #pragma unroll
    for (int j = 0; j < 4; j++)
      #pragma unroll
      for (int h = 0; h < 2; h++)
        bfl[j][h] = *(const long*)&Bs[(64 * wn + 16 * j + frow) * 64 + h * 32 + fq8];
    #pragma unroll
    for (int i = 0; i < 4; i++)
      #pragma unroll
      for (int j = 0; j < 4; j++)
        #pragma unroll
        for (int h = 0; h < 2; h++)
          acc[i][j] = __builtin_amdgcn_mfma_i32_16x16x32_i8(afl[i][h], bfl[j][h], acc[i][j], 0, 0, 0);
#endif
    __syncthreads();
  }
  const float* asc = ascale + (size_t)z * M_ROWS + m0;
  float wsc = wscale[proj];
  int col = lane & 15, rg = lane >> 4;
  #pragma unroll
  for (int i = 0; i < 4; i++) {
    #pragma unroll
    for (int r = 0; r < 4; r++) {
      int mm = 64 * wm + 16 * i + rg * 4 + r;
      float s = asc[mm] * wsc;
      #pragma unroll
      for (int j = 0; j < 4; j++) {
        int nn = 64 * wn + 16 * j + col;
        outF[((size_t)z * M_ROWS + m0 + mm) * DD + (n0 + nn)] = (float)acc[i][j][r] * s;
      }
    }
  }
}

// ---- K5: per-chunk injection; k in LDS (16 KB), v streamed from global ----
__global__ __launch_bounds__(256) void k_inj(const float* __restrict__ rkvg,
                                             const float* __restrict__ log_decay,
                                             float* __restrict__ states) {
  __shared__ float ksh[CH * SS];
  int blk = blockIdx.x, tid = threadIdx.x;
  int n = blk & (NC - 1), h = (blk >> 5) & (HH - 1), b = blk >> 9;
  size_t rowbase = ((size_t)b * TT + n * CH) * DD + h * SS;
  const float* Kp = rkvg + (size_t)1 * M_ROWS * DD + rowbase;
  const float* Vp = rkvg + (size_t)2 * M_ROWS * DD + rowbase;
  for (int idx = tid; idx < CH * SS; idx += 256) {
    int c = idx >> 6, s2 = idx & 63;
    ksh[idx] = Kp[(size_t)c * DD + s2];
  }
  int o = tid & 63, sg = tid >> 6, S0 = sg * 16;
  float wv[16], acc[16];
  #pragma unroll
  for (int j = 0; j < 16; j++) {
    float e = expf(log_decay[h * SS + S0 + j]);
    wv[j] = expf(-e); acc[j] = 0.f;
  }
  __syncthreads();
  for (int ti = 0; ti < 8; ti++) {
    float v8[8];
    #pragma unroll
    for (int tt = 0; tt < 8; tt++)
      v8[tt] = Vp[(size_t)(ti * 8 + tt) * DD + o];
    #pragma unroll
    for (int tt = 0; tt < 8; tt++) {
      int c = ti * 8 + tt;
      float v = v8[tt];
      #pragma unroll
      for (int q = 0; q < 4; q++) {
        float4 k4 = *(const float4*)&ksh[c * SS + S0 + q * 4];
        float kk[4] = {k4.x, k4.y, k4.z, k4.w};
        #pragma unroll
        for (int e = 0; e < 4; e++) {
          int j = q * 4 + e;
          acc[j] = fmaf(wv[j], acc[j], kk[e] * v);
        }
      }
    }
  }
  float* st = states + (size_t)blk * SS * SS;
  #pragma unroll
  for (int j = 0; j < 16; j++) st[(size_t)(S0 + j) * SS + o] = acc[j];
}

// ---- K6: PARALLEL scan — one thread per (b,h,s,o) element. grid 1024. ----
__global__ __launch_bounds__(256) void k_scan(const float* __restrict__ log_decay,
                                              float* __restrict__ states) {
  int blk = blockIdx.x;                 // bh*16 + sb
  int bh = blk >> 4, sb = blk & 15;
  int h = bh & (HH - 1);
  int tid = threadIdx.x;
  int js = tid >> 6, o = tid & 63;
  int s = sb * 4 + js;
  float wC = expf(-64.f * expf(log_decay[h * SS + s]));
  float cur = 0.f;
  float* base = states + (size_t)bh * NC * SS * SS + (size_t)s * SS + o;
  for (int n = 0; n < NC; n++) {
    float* p = base + (size_t)n * SS * SS;
    float inj = *p;
    *p = cur;
    cur = fmaf(wC, cur, inj);
  }
}

// ---- K7: single-backward-pass WKV (unchanged from R9/R10) ----
__global__ __launch_bounds__(256) void k_wkv_y(const float* __restrict__ rkvg,
                                               const float* __restrict__ log_decay,
                                               const float* __restrict__ u,
                                               const float* __restrict__ states,
                                               float* __restrict__ Y) {
  __shared__ float rsh[CH * SS], ksh[CH * SS];   // 32 KB
  __shared__ float part[8 * 4 * SS];             // 8 KB
  __shared__ float betash[CH], eush[SS];
  int blk = blockIdx.x, tid = threadIdx.x;
  int n = blk & (NC - 1), h = (blk >> 5) & (HH - 1), b = blk >> 9;
  size_t rowbase = ((size_t)b * TT + n * CH) * DD + h * SS;
  const float* Rp = rkvg + rowbase;
  const float* Kp = rkvg + (size_t)1 * M_ROWS * DD + rowbase;
  const float* Vp = rkvg + (size_t)2 * M_ROWS * DD + rowbase;
  for (int idx = tid; idx < CH * SS; idx += 256) {
    int c = idx >> 6, s2 = idx & 63;
    rsh[idx] = Rp[(size_t)c * DD + s2];
    ksh[idx] = Kp[(size_t)c * DD + s2];
  }
  if (tid < SS) eush[tid] = expf(u[h * SS + tid]);
  __syncthreads();
  {
    int t = tid >> 2, sq = tid & 3;
    float s = 0.f;
    #pragma unroll
    for (int q = 0; q < 16; q++) {
      int s2 = sq * 16 + ((q + t) & 15);
      s += rsh[t * SS + s2] * ksh[t * SS + s2] * eush[s2];
    }
    s += __shfl_xor(s, 1);
    s += __shfl_xor(s, 2);
    if (sq == 0) betash[t] = s;
  }
  __syncthreads();

  int o = tid & 63, sg = tid >> 6, S0 = sg * 16;
  float wv[16], winv[16], pw[16], st[16], a[16];
  const float* stp = states + (size_t)blk * SS * SS;
  #pragma unroll
  for (int j = 0; j < 16; j++) {
    float e = expf(log_decay[h * SS + S0 + j]);
    wv[j] = expf(-e);
    winv[j] = 1.f / wv[j];
    pw[j] = expf(-64.f * e);                  // w^{64}, exact start (t=63)
    st[j] = stp[(size_t)(S0 + j) * SS + o];
    a[j] = 0.f;
  }
  float* Yb = Y + ((size_t)b * TT + n * CH) * DD + h * SS;
  for (int ti = 7; ti >= 0; ti--) {
    float v8[8];
    #pragma unroll
    for (int tt = 0; tt < 8; tt++)
      v8[tt] = Vp[(size_t)(ti * 8 + tt) * DD + o];
    float p8[8];
    #pragma unroll
    for (int tt = 7; tt >= 0; tt--) {
      int t = ti * 8 + tt;
      float v = v8[tt];
      float acc0 = 0.f, acc1 = 0.f;
      #pragma unroll
      for (int q = 0; q < 4; q++) {
        float4 k4 = *(const float4*)&ksh[t * SS + S0 + q * 4];
        float4 r4 = *(const float4*)&rsh[t * SS + S0 + q * 4];
        float kk[4] = {k4.x, k4.y, k4.z, k4.w};
        float rr[4] = {r4.x, r4.y, r4.z, r4.w};
        #pragma unroll
        for (int e = 0; e < 4; e++) {
          int j = q * 4 + e;
          a[j] = fmaf(wv[j], a[j], kk[e] * v);          // suffix scan
          float bterm = fmaf(pw[j], st[j], a[j]);       // + w^{t+1} state
          if (q < 2) acc0 = fmaf(rr[e], bterm, acc0);
          else       acc1 = fmaf(rr[e], bterm, acc1);
          pw[j] *= winv[j];                              // w^{t+1} -> w^{t}
        }
      }
      float p = acc0 + acc1;
      if (sg == 0) p = fmaf(betash[t], v, p);
      p8[tt] = p;
    }
    #pragma unroll
    for (int tt = 0; tt < 8; tt++) part[tt * 256 + sg * 64 + o] = p8[tt];
    __syncthreads();
    #pragma unroll
    for (int rep = 0; rep < 2; rep++) {
      int e = tid + rep * 256;                 // (tt, o2)
      int tt = e >> 6, o2 = e & 63;
      float s = part[tt * 256 + o2] + part[tt * 256 + 64 + o2]
              + part[tt * 256 + 128 + o2] + part[tt * 256 + 192 + o2];
      Yb[(size_t)(ti * 8 + tt) * DD + o2] = s;
    }
    __syncthreads();
  }
}

// ---- K8 v3: GroupNorm (16-lane shfl stats) + silu + LN + int8 act-quant.
// Thread owns d = tid*4 .. tid*4+3, float4 loads, packed int store. ----
__global__ __launch_bounds__(256) void k_post(const float* __restrict__ Y,
                                              const float* __restrict__ G,
                                              const float* __restrict__ gn_g,
                                              const float* __restrict__ gn_b,
                                              const float* __restrict__ lg,
                                              const float* __restrict__ lb,
                                              char* __restrict__ xq4,
                                              float* __restrict__ ascale4) {
  __shared__ float slots[3 * 4];
  __shared__ float gmean[HH], grstd[HH];
  int m = blockIdx.x, tid = threadIdx.x;
  int d4 = tid * 4;
  float4 y4v = *(const float4*)&Y[(size_t)m * DD + d4];
  float4 g4v = *(const float4*)&G[(size_t)m * DD + d4];
  float y4[4] = {y4v.x, y4v.y, y4v.z, y4v.w};
  float g4[4] = {g4v.x, g4v.y, g4v.z, g4v.w};
  // GN stats: 16 threads/head (head = tid>>4), shfl fold within 16-lane groups
  {
    float s = y4[0] + y4[1] + y4[2] + y4[3];
    s += __shfl_xor(s, 1); s += __shfl_xor(s, 2);
    s += __shfl_xor(s, 4); s += __shfl_xor(s, 8);
    float mn = s * (1.f / SS);
    float v2 = 0.f;
    #pragma unroll
    for (int q = 0; q < 4; q++) { float dv = y4[q] - mn; v2 += dv * dv; }
    v2 += __shfl_xor(v2, 1); v2 += __shfl_xor(v2, 2);
    v2 += __shfl_xor(v2, 4); v2 += __shfl_xor(v2, 8);
    if ((tid & 15) == 0) {
      gmean[tid >> 4] = mn;
      grstd[tid >> 4] = 1.f / sqrtf(v2 * (1.f / SS) + 1e-5f);
    }
  }
  __syncthreads();
  int hh = tid >> 4;
  float4 gg4 = *(const float4*)&gn_g[d4];
  float4 gb4 = *(const float4*)&gn_b[d4];
  float gg[4] = {gg4.x, gg4.y, gg4.z, gg4.w};
  float gb[4] = {gb4.x, gb4.y, gb4.z, gb4.w};
  float z[4];
  #pragma unroll
  for (int j = 0; j < 4; j++) {
    float yn = (y4[j] - gmean[hh]) * grstd[hh] * gg[j] + gb[j];
    float gv = g4[j];
    z[j] = yn * (gv / (1.f + expf(-gv)));            // silu
  }
  float mean = block_sum4(z[0] + z[1] + z[2] + z[3], &slots[0], tid) * (1.f / DD);
  float var = 0.f;
  #pragma unroll
  for (int j = 0; j < 4; j++) { float dv = z[j] - mean; var += dv * dv; }
  var = block_sum4(var, &slots[4], tid) * (1.f / DD);
  float rstd = 1.f / sqrtf(var + 1e-5f);
  float4 lg4 = *(const float4*)&lg[d4];
  float4 lb4 = *(const float4*)&lb[d4];
  float lgv[4] = {lg4.x, lg4.y, lg4.z, lg4.w};
  float lbv[4] = {lb4.x, lb4.y, lb4.z, lb4.w};
  float ln[4]; float aabs = 0.f;
  #pragma unroll
  for (int j = 0; j < 4; j++) {
    ln[j] = (z[j] - mean) * rstd * lgv[j] + lbv[j];
    aabs += fabsf(ln[j]);
  }
  float meanabs = block_sum4(aabs, &slots[8], tid) * (1.f / DD);
  float scale = fmaxf(meanabs, 1e-8f) * 2.5f * (1.f / 127.f);
  int q[4];
  #pragma unroll
  for (int j = 0; j < 4; j++)
    q[j] = (int)rintf(fminf(fmaxf(ln[j] / scale, -127.f), 127.f));
  *(int*)&xq4[(size_t)m * DD + d4] = pack4(q[0], q[1], q[2], q[3]);
  if (tid == 0) ascale4[m] = scale;
}

extern "C" void kernel_launch(void* const* d_in, const int* in_sizes, int n_in,
                              void* d_out, int out_size, void* d_ws, size_t ws_size,
                              hipStream_t stream) {
  // ALL inputs are float32 (verified R4); output float32.
  const float* x         = (const float*)d_in[0];
  const float* mu_r      = (const float*)d_in[1];
  const float* mu_k      = (const float*)d_in[2];
  const float* mu_v      = (const float*)d_in[3];
  const float* mu_g      = (const float*)d_in[4];
  const float* log_decay = (const float*)d_in[5];
  const float* u         = (const float*)d_in[6];
  const float* proj_w    = (const float*)d_in[7];
  const float* ln_g      = (const float*)d_in[8];
  const float* ln_b      = (const float*)d_in[9];
  const float* gn_g      = (const float*)d_in[10];
  const float* gn_b      = (const float*)d_in[11];
  float* out = (float*)d_out;

  // ---- workspace layout, ~205 MiB; U region (40 MB) time-multiplexed:
  //   phase 1: xq slots 0..3 (int8, 4 x 8 MB)    [k_prep_quant -> k_gemm]
  //   phase 2: Y (f32, 32 MB) at U+0             [k_wkv_y -> k_post]
  //   xq4 (int8, 8 MB) at U+32MB                 [k_post -> k_gemm final]
  char* p = (char*)d_ws;
  float*  wscale = (float*)p;  p += 256;                         // 5 f32
  double* wpart  = (double*)p; p += 4096;                        // 5*64 f64
  char*   wq     = (char*)p;   p += (size_t)5 * DD * DD;         // 5 MB
  float*  ascale = (float*)p;  p += (size_t)5 * M_ROWS * 4;      // 160 KB
  char*   U      = p;          p += (size_t)40 * 1024 * 1024;    // 40 MB
  char*   xq     = U;
  float*  Y      = (float*)U;
  char*   xq4    = U + (size_t)M_ROWS * DD * 4;                  // U + 32 MB
  float*  rkvg   = (float*)p;  p += (size_t)4 * M_ROWS * DD * 4; // 128 MB
  float*  states = (float*)p;  p += (size_t)BB * HH * NC * SS * SS * 4; // 32 MB

  hipLaunchKernelGGL(k_wscale_part, dim3(5, 64), dim3(256), 0, stream, proj_w, wpart);
  hipLaunchKernelGGL(k_wscale_fin, dim3(5), dim3(64), 0, stream, wpart, wscale);
  hipLaunchKernelGGL(k_wquant, dim3((5 * DD * DD) / 1024), dim3(256), 0, stream,
                     proj_w, wscale, wq);
  hipLaunchKernelGGL(k_prep_quant, dim3(M_ROWS), dim3(256), 0, stream,
                     x, mu_r, mu_k, mu_v, mu_g, ln_g, ln_b, xq, ascale);
  hipLaunchKernelGGL(k_gemm, dim3(M_ROWS / 128, DD / 128, 4), dim3(256), 0,
                     stream, xq, wq, ascale, wscale, 0, rkvg);
  hipLaunchKernelGGL(k_inj, dim3(BB * HH * NC), dim3(256), 0, stream,
                     rkvg, log_decay, states);
  hipLaunchKernelGGL(k_scan, dim3(BB * HH * 16), dim3(256), 0, stream,
                     log_decay, states);
  hipLaunchKernelGGL(k_wkv_y, dim3(BB * HH * NC), dim3(256), 0, stream,
                     rkvg, log_decay, u, states, Y);
  hipLaunchKernelGGL(k_post, dim3(M_ROWS), dim3(256), 0, stream,
                     Y, rkvg + (size_t)3 * M_ROWS * DD, gn_g, gn_b,
                     ln_g + 4 * DD, ln_b + 4 * DD,
                     xq4, ascale + 4 * M_ROWS);
  hipLaunchKernelGGL(k_gemm, dim3(M_ROWS / 128, DD / 128, 1), dim3(256), 0,
                     stream, xq4, wq,
                     ascale + 4 * M_ROWS, wscale, 4, out);
}